// Round 2
// baseline (217.743 us; speedup 1.0000x reference)
//
#include <hip/hip_runtime.h>

// ColorQuantizer: out[b,c,h,w] = palette[argmin_i dist(processed(x[b,:,h,w]), palette_i)][c]
// processed = relu(x@W1 + b1) @ W2 + b2   (all fp32, replicate reference op order)
//
// This revision: packed-FP32 (VOP3P v_pk_*) math on pixel pairs — 2 f32 per
// instruction — plus an integer-key argmin (v_max_i32 clamp, v_and_or key,
// v_min_u32 tracking with index in low 4 bits). Weights/palette staged
// PRE-DUPLICATED in LDS so pk broadcasts need no v_movs. sq is computed
// bit-exactly in the reference association via a -2*palette fold (power-of-2
// scaling commutes with rounding). Near-ties (incl. the 16-ulp key
// truncation) fall back to the exact sqrt replay, same as the verified R1.

typedef float v2f __attribute__((ext_vector_type(2)));

static __device__ __forceinline__ v2f pk_mul(v2f a, v2f b){
    v2f d; asm("v_pk_mul_f32 %0, %1, %2" : "=v"(d) : "v"(a), "v"(b)); return d; }
static __device__ __forceinline__ v2f pk_add(v2f a, v2f b){
    v2f d; asm("v_pk_add_f32 %0, %1, %2" : "=v"(d) : "v"(a), "v"(b)); return d; }
static __device__ __forceinline__ v2f pk_fma(v2f a, v2f b, v2f c){
    v2f d; asm("v_pk_fma_f32 %0, %1, %2, %3" : "=v"(d) : "v"(a), "v"(b), "v"(c)); return d; }

static __device__ __forceinline__ v2f lo2(float4 v){ v2f r; r.x = v.x; r.y = v.y; return r; }
static __device__ __forceinline__ v2f hi2(float4 v){ v2f r; r.x = v.z; r.y = v.w; return r; }
static __device__ __forceinline__ unsigned umin32(unsigned a, unsigned b){ return a < b ? a : b; }
static __device__ __forceinline__ unsigned umax32(unsigned a, unsigned b){ return a > b ? a : b; }

constexpr int COLI[16][3] = {
  {0,0,0},{255,255,255},{255,0,0},{0,255,0},{0,0,255},{255,255,0},
  {255,0,255},{0,255,255},{128,128,128},{128,0,0},{0,128,0},{0,0,128},
  {128,128,0},{128,0,128},{0,128,128},{192,192,192}
};
constexpr float PVF(int v){ return (float)v/255.0f*2.0f-1.0f; }
constexpr float PXc(int i){ return PVF(COLI[i][0]); }
constexpr float PYc(int i){ return PVF(COLI[i][1]); }
constexpr float PZc(int i){ return PVF(COLI[i][2]); }
// sum(PALETTE*PALETTE, axis=-1) with the reference's reduce order: (x*x + y*y) + z*z
constexpr float PSQc(int i){ return (PXc(i)*PXc(i) + PYc(i)*PYc(i)) + PZc(i)*PZc(i); }

// {px, py, pz, psq} per palette entry (global .rodata, used by staging + fallback).
#define PE(i) {PXc(i), PYc(i), PZc(i), PSQc(i)}
__device__ const float PAL4f[16][4] = {
  PE(0),PE(1),PE(2),PE(3),PE(4),PE(5),PE(6),PE(7),
  PE(8),PE(9),PE(10),PE(11),PE(12),PE(13),PE(14),PE(15)
};

constexpr int HW    = 512*512;   // per-channel plane
constexpr int PXT   = 8;         // pixels per thread (2x float4)
constexpr int BLOCK = 256;

// Rare path: bit-exact replay of the reference distance loop (correctly-rounded
// sqrtf, first-occurrence argmin over d). Taken when the second-min screen says
// sqrt rounding / key truncation could change the winner.
__device__ __attribute__((noinline)) int argmin_exact(float p0, float p1, float p2, float psq)
{
#pragma clang fp contract(off)
    float bd = 3.4e38f;
    int   bi = 0;
#pragma unroll 1
    for (int i = 0; i < 16; ++i) {
        const float px = PAL4f[i][0], py = PAL4f[i][1], pz = PAL4f[i][2], pq = PAL4f[i][3];
        float dot = __builtin_fmaf(p2, pz, __builtin_fmaf(p1, py, p0*px));
        float sq  = (psq - 2.0f*dot) + pq;
        float d   = sqrtf(fmaxf(sq, 0.0f));
        if (d < bd) { bd = d; bi = i; }
    }
    return bi;
}

__global__ __launch_bounds__(BLOCK) void cq_kernel(
    const float* __restrict__ x,  const float* __restrict__ W1g,
    const float* __restrict__ b1g, const float* __restrict__ W2g,
    const float* __restrict__ b2g, float* __restrict__ out)
{
#pragma clang fp contract(off)
    // Pre-duplicated weight/palette tables (one ds_read_b128 = two broadcast pairs):
    //   sWA2[j] = {w0,w0,w1,w1} , {w2,w2,b1j,b1j}
    //   sWB2[j] = {u0,u0,u1,u1} , {u2,u2, 0 , 0 }
    //   sPD[i]  = {-2px,-2px,-2py,-2py} , {-2pz,-2pz,pq,pq}
    //   sPAL[i] = {px,py,pz,pq}   (final gather)
    __shared__ float4 sWA2[32][2];
    __shared__ float4 sWB2[32][2];
    __shared__ float4 sPD[16][2];
    __shared__ float4 sPAL[16];
    __shared__ float4 sB2d[2];

    const int t = threadIdx.x;
    if (t < 32) {
        const float w0 = W1g[t], w1 = W1g[32+t], w2 = W1g[64+t], bb = b1g[t];
        sWA2[t][0] = make_float4(w0, w0, w1, w1);
        sWA2[t][1] = make_float4(w2, w2, bb, bb);
    } else if (t < 64) {
        const int j = t - 32;
        const float u0 = W2g[3*j], u1 = W2g[3*j+1], u2 = W2g[3*j+2];
        sWB2[j][0] = make_float4(u0, u0, u1, u1);
        sWB2[j][1] = make_float4(u2, u2, 0.0f, 0.0f);
    } else if (t < 80) {
        const int i = t - 64;
        const float px = PAL4f[i][0], py = PAL4f[i][1], pz = PAL4f[i][2], pq = PAL4f[i][3];
        sPD[i][0] = make_float4(-2.0f*px, -2.0f*px, -2.0f*py, -2.0f*py);  // exact (pow2 scale)
        sPD[i][1] = make_float4(-2.0f*pz, -2.0f*pz, pq, pq);
        sPAL[i]   = make_float4(px, py, pz, pq);
    } else if (t == 80) {
        const float c0 = b2g[0], c1 = b2g[1], c2 = b2g[2];
        sB2d[0] = make_float4(c0, c0, c1, c1);
        sB2d[1] = make_float4(c2, c2, 0.0f, 0.0f);
    }
    __syncthreads();

    const int pix = (blockIdx.x * BLOCK + t) * PXT;   // < 2^23, int is fine
    const int img = pix >> 18;                        // HW = 2^18
    const int hw  = pix & (HW - 1);
    const size_t base = (size_t)img * (size_t)(3*HW) + (size_t)hw;

    // Load 8 pixels as 4 pixel-pairs per channel.
    v2f X0p[4], X1p[4], X2p[4];
    {
        float4 a0 = *(const float4*)(x + base);
        float4 a1 = *(const float4*)(x + base + 4);
        float4 c0 = *(const float4*)(x + base + HW);
        float4 c1 = *(const float4*)(x + base + HW + 4);
        float4 e0 = *(const float4*)(x + base + 2*HW);
        float4 e1 = *(const float4*)(x + base + 2*HW + 4);
        X0p[0]=lo2(a0); X0p[1]=hi2(a0); X0p[2]=lo2(a1); X0p[3]=hi2(a1);
        X1p[0]=lo2(c0); X1p[1]=hi2(c0); X1p[2]=lo2(c1); X1p[3]=hi2(c1);
        X2p[0]=lo2(e0); X2p[1]=hi2(e0); X2p[2]=lo2(e1); X2p[3]=hi2(e1);
    }

    // processed accumulators; dot runs from 0 so fma(h,u,0) == h*u exactly
    v2f P0p[4], P1p[4], P2p[4];
#pragma unroll
    for (int q = 0; q < 4; ++q) {
        P0p[q] = (v2f)(0.0f); P1p[q] = (v2f)(0.0f); P2p[q] = (v2f)(0.0f);
    }

    // Fused MLP: h = relu(fma(X2,w2, fma(X1,w1, X0*w0)) + b1j); P_c += h*W2[j][c]
#pragma unroll 4
    for (int j = 0; j < 32; ++j) {
        const float4 wa0 = sWA2[j][0];
        const float4 wa1 = sWA2[j][1];
        const float4 wb0 = sWB2[j][0];
        const float4 wb1 = sWB2[j][1];
        const v2f w0p = lo2(wa0), w1p = hi2(wa0), w2p = lo2(wa1), bbp = hi2(wa1);
        const v2f u0p = lo2(wb0), u1p = hi2(wb0), u2p = lo2(wb1);
#pragma unroll
        for (int q = 0; q < 4; ++q) {
            v2f h = pk_mul(X0p[q], w0p);
            h = pk_fma(X1p[q], w1p, h);
            h = pk_fma(X2p[q], w2p, h);
            h = pk_add(h, bbp);
            v2f hr; hr.x = fmaxf(h.x, 0.0f); hr.y = fmaxf(h.y, 0.0f);  // no pk_max_f32
            P0p[q] = pk_fma(hr, u0p, P0p[q]);
            P1p[q] = pk_fma(hr, u1p, P1p[q]);
            P2p[q] = pk_fma(hr, u2p, P2p[q]);
        }
    }

    // Bias + psq in exact reference order: (p0*p0 + p1*p1) + p2*p2
    v2f p0p[4], p1p[4], p2p[4], psqp[4];
    {
        const float4 bd0 = sB2d[0];
        const float4 bd1 = sB2d[1];
        const v2f b0p = lo2(bd0), b1p = hi2(bd0), b2p = lo2(bd1);
#pragma unroll
        for (int q = 0; q < 4; ++q) {
            p0p[q] = pk_add(P0p[q], b0p);
            p1p[q] = pk_add(P1p[q], b1p);
            p2p[q] = pk_add(P2p[q], b2p);
            v2f s0 = pk_mul(p0p[q], p0p[q]);
            v2f s1 = pk_mul(p1p[q], p1p[q]);
            v2f s  = pk_add(s0, s1);
            v2f s2 = pk_mul(p2p[q], p2p[q]);
            psqp[q] = pk_add(s, s2);
        }
    }

    // Distance phase: sq_i = (psq + dot2_i) + pq_i  with dot2 = -2*dot bit-exact.
    // Integer-key argmin: clamp = max_i32(bits(sq),0); key = (clamp & ~15) | i;
    // m1/m2 tracked as u32 mins (index rides in the low 4 bits).
    unsigned m1k[PXT], m2k[PXT];
#pragma unroll
    for (int p = 0; p < PXT; ++p) { m1k[p] = 0xFFFFFFFFu; m2k[p] = 0xFFFFFFFFu; }

#pragma unroll 4
    for (int i = 0; i < 16; ++i) {
        const float4 pd0 = sPD[i][0];
        const float4 pd1 = sPD[i][1];
        const v2f mxp = lo2(pd0), myp = hi2(pd0), mzp = lo2(pd1), pqp = hi2(pd1);
#pragma unroll
        for (int q = 0; q < 4; ++q) {
            v2f d2 = pk_mul(p0p[q], mxp);          // p0*(-2px)  == -2*(p0*px) exactly
            d2 = pk_fma(p1p[q], myp, d2);
            d2 = pk_fma(p2p[q], mzp, d2);
            v2f sq = pk_add(psqp[q], d2);          // == round(psq - 2*dot)  (bit-exact)
            sq = pk_add(sq, pqp);                  // == reference sq        (bit-exact)
            int c0 = __float_as_int(sq.x); c0 = c0 < 0 ? 0 : c0;   // clamp@0, fixes -0
            int c1 = __float_as_int(sq.y); c1 = c1 < 0 ? 0 : c1;
            const unsigned k0 = ((unsigned)c0 & 0xFFFFFFF0u) | (unsigned)i;
            const unsigned k1 = ((unsigned)c1 & 0xFFFFFFF0u) | (unsigned)i;
            const int pa = 2*q, pb = 2*q + 1;
            m2k[pa] = umin32(m2k[pa], umax32(k0, m1k[pa]));
            m1k[pa] = umin32(m1k[pa], k0);
            m2k[pb] = umin32(m2k[pb], umax32(k1, m1k[pb]));
            m1k[pb] = umin32(m1k[pb], k1);
        }
    }

    // Screen: measured gap within 1e-5 relative (covers sqrt-collision ~2ulp +
    // key truncation 2x16ulp) -> replay the reference loop exactly.
    int bi[PXT];
#pragma unroll
    for (int p = 0; p < PXT; ++p) {
        const int q = p >> 1;
        bi[p] = (int)(m1k[p] & 15u);
        const float m1f = __int_as_float((int)(m1k[p] & 0xFFFFFFF0u));
        const float m2f = __int_as_float((int)(m2k[p] & 0xFFFFFFF0u));
        if (__builtin_expect(m2f - m1f <= 1e-5f * m1f, 0)) {
            const float pv0 = (p & 1) ? p0p[q].y : p0p[q].x;
            const float pv1 = (p & 1) ? p1p[q].y : p1p[q].x;
            const float pv2 = (p & 1) ? p2p[q].y : p2p[q].x;
            const float pvq = (p & 1) ? psqp[q].y : psqp[q].x;
            bi[p] = argmin_exact(pv0, pv1, pv2, pvq);
        }
    }

    // Palette gather from LDS + transpose to channel-planar float4 stores.
    float4 col[PXT];
#pragma unroll
    for (int p = 0; p < PXT; ++p) col[p] = sPAL[bi[p]];

    float* op = out + base;   // output has the same [b][c][hw] layout
    float4 o;
    o = make_float4(col[0].x, col[1].x, col[2].x, col[3].x); *(float4*)(op) = o;
    o = make_float4(col[4].x, col[5].x, col[6].x, col[7].x); *(float4*)(op + 4) = o;
    o = make_float4(col[0].y, col[1].y, col[2].y, col[3].y); *(float4*)(op + HW) = o;
    o = make_float4(col[4].y, col[5].y, col[6].y, col[7].y); *(float4*)(op + HW + 4) = o;
    o = make_float4(col[0].z, col[1].z, col[2].z, col[3].z); *(float4*)(op + 2*HW) = o;
    o = make_float4(col[4].z, col[5].z, col[6].z, col[7].z); *(float4*)(op + 2*HW + 4) = o;
}

extern "C" void kernel_launch(void* const* d_in, const int* in_sizes, int n_in,
                              void* d_out, int out_size, void* d_ws, size_t ws_size,
                              hipStream_t stream) {
    const float* x  = (const float*)d_in[0];
    const float* W1 = (const float*)d_in[1];
    const float* b1 = (const float*)d_in[2];
    const float* W2 = (const float*)d_in[3];
    const float* b2 = (const float*)d_in[4];
    float* outp = (float*)d_out;

    constexpr int NPIX = 32 * HW;                    // 8,388,608
    constexpr int GRID = NPIX / (BLOCK * PXT);       // 4096 blocks, exact
    hipLaunchKernelGGL(cq_kernel, dim3(GRID), dim3(BLOCK), 0, stream,
                       x, W1, b1, W2, b2, outp);
}

// Round 3
// 216.295 us; speedup vs baseline: 1.0067x; 1.0067x over previous
//
#include <hip/hip_runtime.h>

// ColorQuantizer: out[b,c,h,w] = palette[argmin_i dist(processed(x[b,:,h,w]), palette_i)][c]
// processed = relu(x@W1 + b1) @ W2 + b2   (all fp32, replicate reference op order)
//
// R3: tied-accumulator v_pk_fma_f32 (no result-move churn), plain v2f vector
// ops for mul/add/relu, FULL unroll of MLP + distance loops (immediate-offset
// ds_read_b128, zero address math, deep compiler prefetch), signed-int argmin
// keys (no per-candidate clamp; m1<=0 routes to the exact fallback), global
// input loads issued before the LDS staging barrier.

typedef float v2f __attribute__((ext_vector_type(2)));

// Tied accumulate: d = a*b + c, in place (dst == src2) -> no copies.
static __device__ __forceinline__ v2f pk_fma(v2f a, v2f b, v2f c){
    asm("v_pk_fma_f32 %0, %1, %2, %0" : "+v"(c) : "v"(a), "v"(b)); return c; }

static __device__ __forceinline__ v2f lo2(float4 v){ v2f r; r.x = v.x; r.y = v.y; return r; }
static __device__ __forceinline__ v2f hi2(float4 v){ v2f r; r.x = v.z; r.y = v.w; return r; }
static __device__ __forceinline__ int imin32(int a, int b){ return a < b ? a : b; }
static __device__ __forceinline__ int imax32(int a, int b){ return a > b ? a : b; }

constexpr int COLI[16][3] = {
  {0,0,0},{255,255,255},{255,0,0},{0,255,0},{0,0,255},{255,255,0},
  {255,0,255},{0,255,255},{128,128,128},{128,0,0},{0,128,0},{0,0,128},
  {128,128,0},{128,0,128},{0,128,128},{192,192,192}
};
constexpr float PVF(int v){ return (float)v/255.0f*2.0f-1.0f; }
constexpr float PXc(int i){ return PVF(COLI[i][0]); }
constexpr float PYc(int i){ return PVF(COLI[i][1]); }
constexpr float PZc(int i){ return PVF(COLI[i][2]); }
// sum(PALETTE*PALETTE, axis=-1) with the reference's reduce order: (x*x + y*y) + z*z
constexpr float PSQc(int i){ return (PXc(i)*PXc(i) + PYc(i)*PYc(i)) + PZc(i)*PZc(i); }

// {px, py, pz, psq} per palette entry (global .rodata, used by staging + fallback).
#define PE(i) {PXc(i), PYc(i), PZc(i), PSQc(i)}
__device__ const float PAL4f[16][4] = {
  PE(0),PE(1),PE(2),PE(3),PE(4),PE(5),PE(6),PE(7),
  PE(8),PE(9),PE(10),PE(11),PE(12),PE(13),PE(14),PE(15)
};

constexpr int HW    = 512*512;   // per-channel plane
constexpr int PXT   = 8;         // pixels per thread (2x float4)
constexpr int BLOCK = 256;

// Rare path: bit-exact replay of the reference distance loop (correctly-rounded
// sqrtf, first-occurrence argmin over d). Taken when the second-min screen says
// sqrt rounding / key truncation / negative-sq could change the winner.
__device__ __attribute__((noinline)) int argmin_exact(float p0, float p1, float p2, float psq)
{
#pragma clang fp contract(off)
    float bd = 3.4e38f;
    int   bi = 0;
#pragma unroll 1
    for (int i = 0; i < 16; ++i) {
        const float px = PAL4f[i][0], py = PAL4f[i][1], pz = PAL4f[i][2], pq = PAL4f[i][3];
        float dot = __builtin_fmaf(p2, pz, __builtin_fmaf(p1, py, p0*px));
        float sq  = (psq - 2.0f*dot) + pq;
        float d   = sqrtf(fmaxf(sq, 0.0f));
        if (d < bd) { bd = d; bi = i; }
    }
    return bi;
}

__global__ __launch_bounds__(BLOCK) void cq_kernel(
    const float* __restrict__ x,  const float* __restrict__ W1g,
    const float* __restrict__ b1g, const float* __restrict__ W2g,
    const float* __restrict__ b2g, float* __restrict__ out)
{
#pragma clang fp contract(off)
    // Pre-duplicated weight/palette tables (one ds_read_b128 = two broadcast pairs):
    //   sWA2[j] = {w0,w0,w1,w1} , {w2,w2,b1j,b1j}
    //   sWB2[j] = {u0,u0,u1,u1} , {u2,u2, 0 , 0 }
    //   sPD[i]  = {-2px,-2px,-2py,-2py} , {-2pz,-2pz,pq,pq}
    //   sPAL[i] = {px,py,pz,pq}   (final gather)
    __shared__ float4 sWA2[32][2];
    __shared__ float4 sWB2[32][2];
    __shared__ float4 sPD[16][2];
    __shared__ float4 sPAL[16];
    __shared__ float4 sB2d[2];

    const int t = threadIdx.x;

    const int pix = (blockIdx.x * BLOCK + t) * PXT;   // < 2^23, int is fine
    const int img = pix >> 18;                        // HW = 2^18
    const int hw  = pix & (HW - 1);
    const size_t base = (size_t)img * (size_t)(3*HW) + (size_t)hw;

    // Issue the 6 input loads BEFORE staging/barrier so HBM/L3 latency hides
    // under the LDS setup.
    float4 a0 = *(const float4*)(x + base);
    float4 a1 = *(const float4*)(x + base + 4);
    float4 c0 = *(const float4*)(x + base + HW);
    float4 c1 = *(const float4*)(x + base + HW + 4);
    float4 e0 = *(const float4*)(x + base + 2*HW);
    float4 e1 = *(const float4*)(x + base + 2*HW + 4);

    if (t < 32) {
        const float w0 = W1g[t], w1 = W1g[32+t], w2 = W1g[64+t], bb = b1g[t];
        sWA2[t][0] = make_float4(w0, w0, w1, w1);
        sWA2[t][1] = make_float4(w2, w2, bb, bb);
    } else if (t < 64) {
        const int j = t - 32;
        const float u0 = W2g[3*j], u1 = W2g[3*j+1], u2 = W2g[3*j+2];
        sWB2[j][0] = make_float4(u0, u0, u1, u1);
        sWB2[j][1] = make_float4(u2, u2, 0.0f, 0.0f);
    } else if (t < 80) {
        const int i = t - 64;
        const float px = PAL4f[i][0], py = PAL4f[i][1], pz = PAL4f[i][2], pq = PAL4f[i][3];
        sPD[i][0] = make_float4(-2.0f*px, -2.0f*px, -2.0f*py, -2.0f*py);  // exact (pow2 scale)
        sPD[i][1] = make_float4(-2.0f*pz, -2.0f*pz, pq, pq);
        sPAL[i]   = make_float4(px, py, pz, pq);
    } else if (t == 80) {
        const float cb0 = b2g[0], cb1 = b2g[1], cb2 = b2g[2];
        sB2d[0] = make_float4(cb0, cb0, cb1, cb1);
        sB2d[1] = make_float4(cb2, cb2, 0.0f, 0.0f);
    }
    __syncthreads();

    v2f X0p[4], X1p[4], X2p[4];
    X0p[0]=lo2(a0); X0p[1]=hi2(a0); X0p[2]=lo2(a1); X0p[3]=hi2(a1);
    X1p[0]=lo2(c0); X1p[1]=hi2(c0); X1p[2]=lo2(c1); X1p[3]=hi2(c1);
    X2p[0]=lo2(e0); X2p[1]=hi2(e0); X2p[2]=lo2(e1); X2p[3]=hi2(e1);

    // processed accumulators; dot runs from 0 so fma(h,u,0) == h*u exactly
    v2f P0p[4], P1p[4], P2p[4];
#pragma unroll
    for (int q = 0; q < 4; ++q) {
        P0p[q] = (v2f)(0.0f); P1p[q] = (v2f)(0.0f); P2p[q] = (v2f)(0.0f);
    }

    // Fused MLP, FULLY unrolled: h = relu(fma(X2,w2, fma(X1,w1, X0*w0)) + b1j);
    // P_c += h*W2[j][c].  All LDS reads become base+imm-offset ds_read_b128.
#pragma unroll
    for (int j = 0; j < 32; ++j) {
        const float4 wa0 = sWA2[j][0];
        const float4 wa1 = sWA2[j][1];
        const float4 wb0 = sWB2[j][0];
        const float4 wb1 = sWB2[j][1];
        const v2f w0p = lo2(wa0), w1p = hi2(wa0), w2p = lo2(wa1), bbp = hi2(wa1);
        const v2f u0p = lo2(wb0), u1p = hi2(wb0), u2p = lo2(wb1);
#pragma unroll
        for (int q = 0; q < 4; ++q) {
            v2f h = X0p[q] * w0p;            // contract-off: stays a mul
            h = pk_fma(X1p[q], w1p, h);
            h = pk_fma(X2p[q], w2p, h);
            h = h + bbp;
            v2f hr; hr.x = fmaxf(h.x, 0.0f); hr.y = fmaxf(h.y, 0.0f);
            P0p[q] = pk_fma(hr, u0p, P0p[q]);
            P1p[q] = pk_fma(hr, u1p, P1p[q]);
            P2p[q] = pk_fma(hr, u2p, P2p[q]);
        }
    }

    // Bias + psq in exact reference order: (p0*p0 + p1*p1) + p2*p2
    v2f p0p[4], p1p[4], p2p[4], psqp[4];
    {
        const float4 bd0 = sB2d[0];
        const float4 bd1 = sB2d[1];
        const v2f b0p = lo2(bd0), b1p = hi2(bd0), b2p = lo2(bd1);
#pragma unroll
        for (int q = 0; q < 4; ++q) {
            p0p[q] = P0p[q] + b0p;
            p1p[q] = P1p[q] + b1p;
            p2p[q] = P2p[q] + b2p;
            v2f s0 = p0p[q] * p0p[q];
            v2f s1 = p1p[q] * p1p[q];
            v2f s  = s0 + s1;
            v2f s2 = p2p[q] * p2p[q];
            psqp[q] = s + s2;
        }
    }

    // Distance phase (fully unrolled): sq_i = (psq + dot2_i) + pq_i, dot2 = -2*dot
    // bit-exact (pow2 scale commutes with rounding). Argmin via SIGNED int keys:
    // for sq >= 0, i32 bit-order == float order; any negative sq makes m1 < 0
    // and routes to the exact fallback. key = (bits & ~15) | i keeps the index
    // in the low 4 bits (first-occurrence on exact ties).
    int m1k[PXT], m2k[PXT];
#pragma unroll
    for (int p = 0; p < PXT; ++p) { m1k[p] = 0x7FFFFFFF; m2k[p] = 0x7FFFFFFF; }

#pragma unroll
    for (int i = 0; i < 16; ++i) {
        const float4 pd0 = sPD[i][0];
        const float4 pd1 = sPD[i][1];
        const v2f mxp = lo2(pd0), myp = hi2(pd0), mzp = lo2(pd1), pqp = hi2(pd1);
#pragma unroll
        for (int q = 0; q < 4; ++q) {
            v2f d2 = p0p[q] * mxp;                 // p0*(-2px) == -2*(p0*px) exactly
            d2 = pk_fma(p1p[q], myp, d2);
            d2 = pk_fma(p2p[q], mzp, d2);
            v2f sq = psqp[q] + d2;                 // == round(psq - 2*dot)  (bit-exact)
            sq = sq + pqp;                         // == reference sq        (bit-exact)
            const int k0 = (__float_as_int(sq.x) & (int)0xFFFFFFF0) | i;
            const int k1 = (__float_as_int(sq.y) & (int)0xFFFFFFF0) | i;
            const int pa = 2*q, pb = 2*q + 1;
            m2k[pa] = imin32(m2k[pa], imax32(k0, m1k[pa]));   // uses OLD m1
            m1k[pa] = imin32(m1k[pa], k0);
            m2k[pb] = imin32(m2k[pb], imax32(k1, m1k[pb]));
            m1k[pb] = imin32(m1k[pb], k1);
        }
    }

    // Screen: fallback if min is non-positive (negative/zero sq zone, where the
    // int ordering diverges from clamp semantics) or the relative gap is within
    // 3e-5 (covers 2x16-ulp key truncation + sqrt rounding collisions).
    int bi[PXT];
#pragma unroll
    for (int p = 0; p < PXT; ++p) {
        const int q = p >> 1;
        bi[p] = m1k[p] & 15;
        const float m1f = __int_as_float(m1k[p] & (int)0xFFFFFFF0);
        const float m2f = __int_as_float(m2k[p] & (int)0xFFFFFFF0);
        if (__builtin_expect(m1f <= 0.0f || (m2f - m1f) <= 3e-5f * m1f, 0)) {
            const float pv0 = (p & 1) ? p0p[q].y : p0p[q].x;
            const float pv1 = (p & 1) ? p1p[q].y : p1p[q].x;
            const float pv2 = (p & 1) ? p2p[q].y : p2p[q].x;
            const float pvq = (p & 1) ? psqp[q].y : psqp[q].x;
            bi[p] = argmin_exact(pv0, pv1, pv2, pvq);
        }
    }

    // Palette gather from LDS + transpose to channel-planar float4 stores.
    float4 col[PXT];
#pragma unroll
    for (int p = 0; p < PXT; ++p) col[p] = sPAL[bi[p]];

    float* op = out + base;   // output has the same [b][c][hw] layout
    float4 o;
    o = make_float4(col[0].x, col[1].x, col[2].x, col[3].x); *(float4*)(op) = o;
    o = make_float4(col[4].x, col[5].x, col[6].x, col[7].x); *(float4*)(op + 4) = o;
    o = make_float4(col[0].y, col[1].y, col[2].y, col[3].y); *(float4*)(op + HW) = o;
    o = make_float4(col[4].y, col[5].y, col[6].y, col[7].y); *(float4*)(op + HW + 4) = o;
    o = make_float4(col[0].z, col[1].z, col[2].z, col[3].z); *(float4*)(op + 2*HW) = o;
    o = make_float4(col[4].z, col[5].z, col[6].z, col[7].z); *(float4*)(op + 2*HW + 4) = o;
}

extern "C" void kernel_launch(void* const* d_in, const int* in_sizes, int n_in,
                              void* d_out, int out_size, void* d_ws, size_t ws_size,
                              hipStream_t stream) {
    const float* x  = (const float*)d_in[0];
    const float* W1 = (const float*)d_in[1];
    const float* b1 = (const float*)d_in[2];
    const float* W2 = (const float*)d_in[3];
    const float* b2 = (const float*)d_in[4];
    float* outp = (float*)d_out;

    constexpr int NPIX = 32 * HW;                    // 8,388,608
    constexpr int GRID = NPIX / (BLOCK * PXT);       // 4096 blocks, exact
    hipLaunchKernelGGL(cq_kernel, dim3(GRID), dim3(BLOCK), 0, stream,
                       x, W1, b1, W2, b2, outp);
}

// Round 4
// 212.606 us; speedup vs baseline: 1.0242x; 1.0174x over previous
//
#include <hip/hip_runtime.h>

// ColorQuantizer: out[b,c,h,w] = palette[argmin_i dist(processed(x[b,:,h,w]), palette_i)][c]
// processed = relu(x@W1 + b1) @ W2 + b2   (all fp32, replicate reference op order)
//
// R4: LDS traffic halved — compact float4 tables with VOP3P op_sel broadcasts
// (both result halves read one chosen 32-bit half of the 64-bit source), so no
// pre-duplicated pairs and only ONE ds_read_b128 per table per j/i. Unit-stride
// pixel remap (thread owns 4t..4t+3 and 1024+4t..+3): every global load/store
// is a fully-packed contiguous 1KB wave transaction with full-line writes.
// Bounded unroll (x4) to keep VGPR pressure sane. Numerics identical to the
// verified R3 (absmax=0): same op order, -2*palette fold, int-key argmin,
// screen + exact sqrt fallback.

typedef float v2f __attribute__((ext_vector_type(2)));

// VOP3P packed-f32 helpers. _blo: both halves use src1.lo; _bhi: src1.hi.
// Tied accumulators ("+v") -> no result moves.
static __device__ __forceinline__ v2f pk_mul_blo(v2f a, v2f b){
    v2f d; asm("v_pk_mul_f32 %0, %1, %2 op_sel:[0,0] op_sel_hi:[1,0]"
               : "=v"(d) : "v"(a), "v"(b)); return d; }
static __device__ __forceinline__ v2f pk_fma_blo(v2f a, v2f b, v2f c){
    asm("v_pk_fma_f32 %0, %1, %2, %0 op_sel:[0,0,0] op_sel_hi:[1,0,1]"
        : "+v"(c) : "v"(a), "v"(b)); return c; }
static __device__ __forceinline__ v2f pk_fma_bhi(v2f a, v2f b, v2f c){
    asm("v_pk_fma_f32 %0, %1, %2, %0 op_sel:[0,1,0] op_sel_hi:[1,1,1]"
        : "+v"(c) : "v"(a), "v"(b)); return c; }
static __device__ __forceinline__ v2f pk_add_blo(v2f a, v2f b){   // a + {b.lo,b.lo}
    asm("v_pk_add_f32 %0, %0, %1 op_sel:[0,0] op_sel_hi:[1,0]"
        : "+v"(a) : "v"(b)); return a; }
static __device__ __forceinline__ v2f pk_add_bhi(v2f a, v2f b){   // a + {b.hi,b.hi}
    asm("v_pk_add_f32 %0, %0, %1 op_sel:[0,1] op_sel_hi:[1,1]"
        : "+v"(a) : "v"(b)); return a; }
static __device__ __forceinline__ v2f pk_add(v2f a, v2f b){       // a + b (tied)
    asm("v_pk_add_f32 %0, %0, %1" : "+v"(a) : "v"(b)); return a; }
static __device__ __forceinline__ v2f pk_mul(v2f a, v2f b){
    v2f d; asm("v_pk_mul_f32 %0, %1, %2" : "=v"(d) : "v"(a), "v"(b)); return d; }

static __device__ __forceinline__ v2f lo2(float4 v){ v2f r; r.x = v.x; r.y = v.y; return r; }
static __device__ __forceinline__ v2f hi2(float4 v){ v2f r; r.x = v.z; r.y = v.w; return r; }
static __device__ __forceinline__ int imin32(int a, int b){ return a < b ? a : b; }
static __device__ __forceinline__ int imax32(int a, int b){ return a > b ? a : b; }

constexpr int COLI[16][3] = {
  {0,0,0},{255,255,255},{255,0,0},{0,255,0},{0,0,255},{255,255,0},
  {255,0,255},{0,255,255},{128,128,128},{128,0,0},{0,128,0},{0,0,128},
  {128,128,0},{128,0,128},{0,128,128},{192,192,192}
};
constexpr float PVF(int v){ return (float)v/255.0f*2.0f-1.0f; }
constexpr float PXc(int i){ return PVF(COLI[i][0]); }
constexpr float PYc(int i){ return PVF(COLI[i][1]); }
constexpr float PZc(int i){ return PVF(COLI[i][2]); }
// sum(PALETTE*PALETTE, axis=-1) with the reference's reduce order: (x*x + y*y) + z*z
constexpr float PSQc(int i){ return (PXc(i)*PXc(i) + PYc(i)*PYc(i)) + PZc(i)*PZc(i); }

// {px, py, pz, psq} per palette entry (global .rodata, used by staging + fallback).
#define PE(i) {PXc(i), PYc(i), PZc(i), PSQc(i)}
__device__ const float PAL4f[16][4] = {
  PE(0),PE(1),PE(2),PE(3),PE(4),PE(5),PE(6),PE(7),
  PE(8),PE(9),PE(10),PE(11),PE(12),PE(13),PE(14),PE(15)
};

constexpr int HW    = 512*512;   // per-channel plane
constexpr int PXT   = 8;         // pixels per thread (2 unit-stride float4 groups)
constexpr int BLOCK = 256;

// Rare path: bit-exact replay of the reference distance loop (correctly-rounded
// sqrtf, first-occurrence argmin over d).
__device__ __attribute__((noinline)) int argmin_exact(float p0, float p1, float p2, float psq)
{
#pragma clang fp contract(off)
    float bd = 3.4e38f;
    int   bi = 0;
#pragma unroll 1
    for (int i = 0; i < 16; ++i) {
        const float px = PAL4f[i][0], py = PAL4f[i][1], pz = PAL4f[i][2], pq = PAL4f[i][3];
        float dot = __builtin_fmaf(p2, pz, __builtin_fmaf(p1, py, p0*px));
        float sq  = (psq - 2.0f*dot) + pq;
        float d   = sqrtf(fmaxf(sq, 0.0f));
        if (d < bd) { bd = d; bi = i; }
    }
    return bi;
}

__global__ __launch_bounds__(BLOCK) void cq_kernel(
    const float* __restrict__ x,  const float* __restrict__ W1g,
    const float* __restrict__ b1g, const float* __restrict__ W2g,
    const float* __restrict__ b2g, float* __restrict__ out)
{
#pragma clang fp contract(off)
    // Compact tables (ONE ds_read_b128 each; op_sel does the broadcasting):
    //   sWA[j] = {w0, w1, w2, b1j}
    //   sWB[j] = {u0, u1, u2, 0}
    //   sPD[i] = {-2px, -2py, -2pz, pq}
    //   sPAL[i]= {px, py, pz, pq}     (final gather)
    __shared__ float4 sWA[32];
    __shared__ float4 sWB[32];
    __shared__ float4 sPD[16];
    __shared__ float4 sPAL[16];
    __shared__ float4 sB2c;

    const int t = threadIdx.x;

    // Block-uniform base: 128 blocks per image, 2048 px per block.
    const int img = blockIdx.x >> 7;
    const int hwb = (blockIdx.x & 127) << 11;
    const size_t base = (size_t)img * (size_t)(3*HW) + (size_t)hwb;
    const int oa = 4*t;           // group A: pixels [4t, 4t+4)
    const int ob = 4*t + 1024;    // group B: pixels [1024+4t, 1024+4t+4)

    // Issue the 6 unit-stride input loads BEFORE staging so latency hides.
    float4 a0 = *(const float4*)(x + base + oa);
    float4 a1 = *(const float4*)(x + base + ob);
    float4 c0 = *(const float4*)(x + base + HW + oa);
    float4 c1 = *(const float4*)(x + base + HW + ob);
    float4 e0 = *(const float4*)(x + base + 2*HW + oa);
    float4 e1 = *(const float4*)(x + base + 2*HW + ob);

    if (t < 32) {
        sWA[t] = make_float4(W1g[t], W1g[32+t], W1g[64+t], b1g[t]);
    } else if (t < 64) {
        const int j = t - 32;
        sWB[j] = make_float4(W2g[3*j], W2g[3*j+1], W2g[3*j+2], 0.0f);
    } else if (t < 80) {
        const int i = t - 64;
        const float px = PAL4f[i][0], py = PAL4f[i][1], pz = PAL4f[i][2], pq = PAL4f[i][3];
        sPD[i]  = make_float4(-2.0f*px, -2.0f*py, -2.0f*pz, pq);  // -2x exact (pow2)
        sPAL[i] = make_float4(px, py, pz, pq);
    } else if (t == 80) {
        sB2c = make_float4(b2g[0], b2g[1], b2g[2], 0.0f);
    }
    __syncthreads();

    // Pixel pairs: q=0,1 -> group A (pixels 4t+0..3), q=2,3 -> group B.
    v2f X0p[4], X1p[4], X2p[4];
    X0p[0]=lo2(a0); X0p[1]=hi2(a0); X0p[2]=lo2(a1); X0p[3]=hi2(a1);
    X1p[0]=lo2(c0); X1p[1]=hi2(c0); X1p[2]=lo2(c1); X1p[3]=hi2(c1);
    X2p[0]=lo2(e0); X2p[1]=hi2(e0); X2p[2]=lo2(e1); X2p[3]=hi2(e1);

    // processed accumulators; dot runs from 0 so fma(h,u,0) == h*u exactly
    v2f P0p[4], P1p[4], P2p[4];
#pragma unroll
    for (int q = 0; q < 4; ++q) {
        P0p[q] = (v2f)(0.0f); P1p[q] = (v2f)(0.0f); P2p[q] = (v2f)(0.0f);
    }

    // Fused MLP: h = relu(fma(X2,w2, fma(X1,w1, X0*w0)) + b1j); P_c += h*W2[j][c]
    // One ds_read_b128 per table per j; op_sel broadcasts each scalar.
#pragma unroll 4
    for (int j = 0; j < 32; ++j) {
        const float4 wa = sWA[j];
        const float4 wb = sWB[j];
        const v2f w01 = lo2(wa), w2b = hi2(wa);   // {w0,w1}, {w2,bb}
        const v2f u01 = lo2(wb), u2z = hi2(wb);   // {u0,u1}, {u2,0}
#pragma unroll
        for (int q = 0; q < 4; ++q) {
            v2f h = pk_mul_blo(X0p[q], w01);          // * w0
            h = pk_fma_bhi(X1p[q], w01, h);           // + X1*w1
            h = pk_fma_blo(X2p[q], w2b, h);           // + X2*w2
            h = pk_add_bhi(h, w2b);                   // + bb
            v2f hr; hr.x = fmaxf(h.x, 0.0f); hr.y = fmaxf(h.y, 0.0f);
            P0p[q] = pk_fma_blo(hr, u01, P0p[q]);     // += h*u0
            P1p[q] = pk_fma_bhi(hr, u01, P1p[q]);     // += h*u1
            P2p[q] = pk_fma_blo(hr, u2z, P2p[q]);     // += h*u2
        }
    }

    // Bias + psq in exact reference order: (p0*p0 + p1*p1) + p2*p2
    v2f p0p[4], p1p[4], p2p[4], psqp[4];
    {
        const float4 b2c = sB2c;
        const v2f bc01 = lo2(b2c), bc2z = hi2(b2c);   // {c0,c1}, {c2,0}
#pragma unroll
        for (int q = 0; q < 4; ++q) {
            p0p[q] = pk_add_blo(P0p[q], bc01);
            p1p[q] = pk_add_bhi(P1p[q], bc01);
            p2p[q] = pk_add_blo(P2p[q], bc2z);
            v2f s0 = pk_mul(p0p[q], p0p[q]);
            v2f s1 = pk_mul(p1p[q], p1p[q]);
            v2f s  = pk_add(s0, s1);
            v2f s2 = pk_mul(p2p[q], p2p[q]);
            psqp[q] = pk_add(s, s2);
        }
    }

    // Distance phase: sq_i = (psq + dot2_i) + pq_i with dot2 = -2*dot bit-exact
    // (pow2 scale commutes with rounding). SIGNED int-key argmin: for sq >= 0,
    // i32 bit-order == float order; m1 <= 0 routes to the exact fallback.
    // key = (bits & ~15) | i keeps the index in the low 4 bits.
    int m1k[PXT], m2k[PXT];
#pragma unroll
    for (int p = 0; p < PXT; ++p) { m1k[p] = 0x7FFFFFFF; m2k[p] = 0x7FFFFFFF; }

#pragma unroll 4
    for (int i = 0; i < 16; ++i) {
        const float4 pd = sPD[i];
        const v2f mxy = lo2(pd), mzq = hi2(pd);       // {-2px,-2py}, {-2pz,pq}
#pragma unroll
        for (int q = 0; q < 4; ++q) {
            v2f d2 = pk_mul_blo(p0p[q], mxy);         // p0*(-2px)
            d2 = pk_fma_bhi(p1p[q], mxy, d2);         // + p1*(-2py)
            d2 = pk_fma_blo(p2p[q], mzq, d2);         // + p2*(-2pz)
            v2f sq = pk_add(d2, psqp[q]);             // == round(psq - 2*dot)
            sq = pk_add_bhi(sq, mzq);                 // + pq  == reference sq
            const int k0 = (__float_as_int(sq.x) & (int)0xFFFFFFF0) | i;
            const int k1 = (__float_as_int(sq.y) & (int)0xFFFFFFF0) | i;
            const int pa = 2*q, pb = 2*q + 1;
            m2k[pa] = imin32(m2k[pa], imax32(k0, m1k[pa]));   // uses OLD m1
            m1k[pa] = imin32(m1k[pa], k0);
            m2k[pb] = imin32(m2k[pb], imax32(k1, m1k[pb]));
            m1k[pb] = imin32(m1k[pb], k1);
        }
    }

    // Screen: fallback if min non-positive or relative gap within 3e-5
    // (covers 2x16-ulp key truncation + sqrt rounding collisions).
    int bi[PXT];
#pragma unroll
    for (int p = 0; p < PXT; ++p) {
        const int q = p >> 1;
        bi[p] = m1k[p] & 15;
        const float m1f = __int_as_float(m1k[p] & (int)0xFFFFFFF0);
        const float m2f = __int_as_float(m2k[p] & (int)0xFFFFFFF0);
        if (__builtin_expect(m1f <= 0.0f || (m2f - m1f) <= 3e-5f * m1f, 0)) {
            const float pv0 = (p & 1) ? p0p[q].y : p0p[q].x;
            const float pv1 = (p & 1) ? p1p[q].y : p1p[q].x;
            const float pv2 = (p & 1) ? p2p[q].y : p2p[q].x;
            const float pvq = (p & 1) ? psqp[q].y : psqp[q].x;
            bi[p] = argmin_exact(pv0, pv1, pv2, pvq);
        }
    }

    // Palette gather from LDS + transpose to channel-planar unit-stride stores.
    float4 col[PXT];
#pragma unroll
    for (int p = 0; p < PXT; ++p) col[p] = sPAL[bi[p]];

    float* op = out + base;
    float4 o;
    o = make_float4(col[0].x, col[1].x, col[2].x, col[3].x); *(float4*)(op + oa) = o;
    o = make_float4(col[4].x, col[5].x, col[6].x, col[7].x); *(float4*)(op + ob) = o;
    o = make_float4(col[0].y, col[1].y, col[2].y, col[3].y); *(float4*)(op + HW + oa) = o;
    o = make_float4(col[4].y, col[5].y, col[6].y, col[7].y); *(float4*)(op + HW + ob) = o;
    o = make_float4(col[0].z, col[1].z, col[2].z, col[3].z); *(float4*)(op + 2*HW + oa) = o;
    o = make_float4(col[4].z, col[5].z, col[6].z, col[7].z); *(float4*)(op + 2*HW + ob) = o;
}

extern "C" void kernel_launch(void* const* d_in, const int* in_sizes, int n_in,
                              void* d_out, int out_size, void* d_ws, size_t ws_size,
                              hipStream_t stream) {
    const float* x  = (const float*)d_in[0];
    const float* W1 = (const float*)d_in[1];
    const float* b1 = (const float*)d_in[2];
    const float* W2 = (const float*)d_in[3];
    const float* b2 = (const float*)d_in[4];
    float* outp = (float*)d_out;

    constexpr int NPIX = 32 * HW;                    // 8,388,608
    constexpr int GRID = NPIX / (BLOCK * PXT);       // 4096 blocks, exact
    hipLaunchKernelGGL(cq_kernel, dim3(GRID), dim3(BLOCK), 0, stream,
                       x, W1, b1, W2, b2, outp);
}